// Round 18
// baseline (140.596 us; speedup 1.0000x reference)
//
#include <hip/hip_runtime.h>

typedef __bf16 bf16;
typedef __bf16 bf16x4 __attribute__((ext_vector_type(4)));
typedef __bf16 bf16x8 __attribute__((ext_vector_type(8)));
typedef float f32x4 __attribute__((ext_vector_type(4)));

#define MFMA16(a, b, c) __builtin_amdgcn_mfma_f32_16x16x32_bf16((a), (b), (c), 0, 0, 0)

__device__ inline float fexp2(float x) {
    float r;
    asm("v_exp_f32 %0, %1" : "=v"(r) : "v"(x));
    return r;
}

// ---------------------------------------------------------------------------
// K1: fused pre-pass.  blocks 0-255: transpose x [256][4096] f32 ->
// xt [4096][256] bf16 (LDS-tiled).  blocks 256+: fused weights
// Wq/Wk/Wv = w2 @ w1 [512][256] bf16 + wo/wg -> bf16.
// ---------------------------------------------------------------------------
__global__ void k_pre(const float* __restrict__ x, bf16* __restrict__ xt,
                      const float* __restrict__ wq1, const float* __restrict__ wk1,
                      const float* __restrict__ wv1, const float* __restrict__ wq2,
                      const float* __restrict__ wk2, const float* __restrict__ wv2,
                      const float* __restrict__ wo, const float* __restrict__ wg,
                      bf16* __restrict__ Wq, bf16* __restrict__ Wk, bf16* __restrict__ Wv,
                      bf16* __restrict__ wo_bf, bf16* __restrict__ wg_bf) {
    __shared__ float tile[64][68];
    const int bx = blockIdx.x;
    if (bx < 256) {
        const int t = threadIdx.x;
        const int c0 = (bx & 3) * 64;
        const int n0 = (bx >> 2) * 64;
        {
            const int cr = t >> 4, nc = (t & 15) * 4;
#pragma unroll
            for (int i = 0; i < 4; ++i) {
                const float4 v = *(const float4*)(x + (size_t)(c0 + cr + i * 16) * 4096 + n0 + nc);
                tile[cr + i * 16][nc + 0] = v.x;
                tile[cr + i * 16][nc + 1] = v.y;
                tile[cr + i * 16][nc + 2] = v.z;
                tile[cr + i * 16][nc + 3] = v.w;
            }
        }
        __syncthreads();
        const int n = t >> 2, cc = (t & 3) * 16;
        bf16x8 o0, o1;
#pragma unroll
        for (int j = 0; j < 8; ++j) o0[j] = (bf16)tile[cc + j][n];
#pragma unroll
        for (int j = 0; j < 8; ++j) o1[j] = (bf16)tile[cc + 8 + j][n];
        bf16* dst = xt + (size_t)(n0 + n) * 256 + c0 + cc;
        *(bf16x8*)dst = o0;
        *(bf16x8*)(dst + 8) = o1;
    } else {
        int t = (bx - 256) * 256 + threadIdx.x;
        if (t < 393216) {                       // 3 * 512 * 256
            int which = t >> 17;
            int rem = t & 131071;
            int o = rem >> 8, c = rem & 255;
            const float* w1 = which == 0 ? wq1 : which == 1 ? wk1 : wv1;
            const float* w2 = which == 0 ? wq2 : which == 1 ? wk2 : wv2;
            float acc = 0.f;
#pragma unroll
            for (int j = 0; j < 32; ++j) acc += w2[o * 32 + j] * w1[j * 256 + c];
            bf16* W = which == 0 ? Wq : which == 1 ? Wk : Wv;
            W[o * 256 + c] = (bf16)acc;
        } else if (t < 524288) {                // wo: 256*512
            int idx = t - 393216;
            wo_bf[idx] = (bf16)wo[idx];
        } else if (t < 589824) {                // wg: 256*256
            int idx = t - 524288;
            wg_bf[idx] = (bf16)wg[idx];
        }
    }
}

// ---------------------------------------------------------------------------
// GEMM-NT body (tile 128x64): C[i][j] = sum_k A[i][k]*B[j][k].
// MODE 0: -> bf16 [j>>6][i][j&63] with scale; MODE 1: -> bf16 [i][j].
// ---------------------------------------------------------------------------
template <int MODE>
__device__ __forceinline__ void gemm_body(const bf16* __restrict__ A, const bf16* __restrict__ B,
                                          int K, float scale, void* __restrict__ outp,
                                          int bx, int by) {
    const int lane = threadIdx.x & 63;
    const int w = threadIdx.x >> 6;
    const int i0 = by * 128 + w * 32;
    const int j0 = bx * 64;
    const int lrow = lane & 15;
    const int lk = (lane >> 4) * 8;

    f32x4 acc[2][4];
#pragma unroll
    for (int a = 0; a < 2; ++a)
#pragma unroll
        for (int b = 0; b < 4; ++b) acc[a][b] = (f32x4){0.f, 0.f, 0.f, 0.f};

    for (int k0 = 0; k0 < K; k0 += 32) {
        bf16x8 af[2], bfr[4];
#pragma unroll
        for (int qs = 0; qs < 2; ++qs)
            af[qs] = *(const bf16x8*)(A + (size_t)(i0 + qs * 16 + lrow) * K + k0 + lk);
#pragma unroll
        for (int js = 0; js < 4; ++js)
            bfr[js] = *(const bf16x8*)(B + (size_t)(j0 + js * 16 + lrow) * K + k0 + lk);
#pragma unroll
        for (int qs = 0; qs < 2; ++qs)
#pragma unroll
            for (int js = 0; js < 4; ++js)
                acc[qs][js] = MFMA16(af[qs], bfr[js], acc[qs][js]);
    }

    const int rbase = (lane >> 4) * 4;
#pragma unroll
    for (int qs = 0; qs < 2; ++qs)
#pragma unroll
        for (int js = 0; js < 4; ++js)
#pragma unroll
            for (int r = 0; r < 4; ++r) {
                int i = i0 + qs * 16 + rbase + r;
                int j = j0 + js * 16 + lrow;
                float v = acc[qs][js][r];
                if (MODE == 0) {
                    ((bf16*)outp)[(size_t)(j >> 6) * (4096 * 64) + (size_t)i * 64 + (j & 63)] =
                        (bf16)(v * scale);
                } else {
                    ((bf16*)outp)[(size_t)i * 4096 + j] = (bf16)v;
                }
            }
}

// ---------------------------------------------------------------------------
// K3: merged Q/K/V projection -- one 768-block launch.
// ---------------------------------------------------------------------------
__launch_bounds__(256)
__global__ void k_qkv(const bf16* __restrict__ xbf, const bf16* __restrict__ Wq,
                      const bf16* __restrict__ Wk, const bf16* __restrict__ Wv,
                      bf16* __restrict__ q_buf, bf16* __restrict__ k_buf,
                      bf16* __restrict__ vT, float qscale) {
    const int b = blockIdx.x;
    if (b < 256) {
        gemm_body<0>(xbf, Wq, 256, qscale, q_buf, b & 7, b >> 3);
    } else if (b < 512) {
        const int bb = b - 256;
        gemm_body<0>(xbf, Wk, 256, 1.0f, k_buf, bb & 7, bb >> 3);
    } else {
        const int bb = b - 512;
        gemm_body<1>(Wv, xbf, 256, 1.0f, vT, bb & 63, bb >> 6);
    }
}

// ---------------------------------------------------------------------------
// K4: flash attention, KV-split S=4, static-max softmax (exp2, shift=0).
// R16 proven config (best measured: 54.2us): single 16KB KV buffer, zero4
// C-operand trick, K/V fragments read once shared across qs halves,
// ones-MFMA row-sum, lambda-free, reg-staged prefetch, setprio on MFMA.
// grid = 1024 (split<<8 | h<<5 | qt), block = 256 (4 waves x 32 q-rows).
// ---------------------------------------------------------------------------
__launch_bounds__(256)
__global__ void k_attn(const bf16* __restrict__ q, const bf16* __restrict__ k,
                       const bf16* __restrict__ vT, bf16* __restrict__ Opart,
                       float* __restrict__ lpart) {
    __shared__ char kvlds[16384];           // K [64 rows][128B] at 0, V at 8192
    __shared__ char plds[4][4096];          // per-wave P [32 rows][128B]
    const int tid = threadIdx.x;
    const int lane = tid & 63;
    const int w = tid >> 6;
    const int split = blockIdx.x >> 8;
    const int h = (blockIdx.x >> 5) & 7;
    const int qt = blockIdx.x & 31;
    const int qbase = qt * 128 + w * 32;
    const int lrow = lane & 15;
    const int g = lane >> 4;
    const int swzr = (lrow & 7) << 4;

    const bf16* qh = q + (size_t)h * 4096 * 64;
    const bf16* kh = k + (size_t)h * 4096 * 64;
    const bf16* vh = vT + (size_t)h * 64 * 4096;
    char* myp = plds[w];
    const char* Kl = kvlds;
    const char* Vl = kvlds + 8192;

    // staging geometry: threads 0-127 stage K (8KB), 128-255 stage V (8KB)
    const int isV = tid >> 7;
    const int srow = (tid & 127) >> 1;
    const int shalf = tid & 1;
    const int swzs = (srow & 7) << 4;
    char* ldst = kvlds + isV * 8192 + srow * 128;
    const bf16* sbase = isV ? (vh + (size_t)srow * 4096 + split * 1024 + shalf * 32)
                            : (kh + ((size_t)split * 1024 + srow) * 64 + shalf * 32);
    const size_t sstep = isV ? 64 : 64 * 64;   // elements per tile step

    // Q as B-fragments (col = q-row = lane&15)
    bf16x8 bq[2][2];
#pragma unroll
    for (int qs = 0; qs < 2; ++qs)
#pragma unroll
        for (int ks = 0; ks < 2; ++ks)
            bq[qs][ks] = *(const bf16x8*)(qh + (size_t)(qbase + qs * 16 + lrow) * 64 +
                                          ks * 32 + g * 8);

    f32x4 accO[2][4];
    f32x4 l_acc[2];
#pragma unroll
    for (int qs = 0; qs < 2; ++qs) {
#pragma unroll
        for (int ds = 0; ds < 4; ++ds) accO[qs][ds] = (f32x4){0.f, 0.f, 0.f, 0.f};
        l_acc[qs] = (f32x4){0.f, 0.f, 0.f, 0.f};
    }
    const f32x4 zero4 = (f32x4){0.f, 0.f, 0.f, 0.f};   // loop-invariant C=0
    bf16x8 ones;
#pragma unroll
    for (int i = 0; i < 8; ++i) ones[i] = (bf16)1.0f;

    // prologue: stage tile 0 into regs
    uint4 r0, r1, r2, r3;
    {
        const bf16* p = sbase;
        r0 = *(const uint4*)(p);
        r1 = *(const uint4*)(p + 8);
        r2 = *(const uint4*)(p + 16);
        r3 = *(const uint4*)(p + 24);
    }

    for (int t = 0; t < 16; ++t) {
        // ---- write staged tile to LDS (XOR-swizzled rows) ----
        *(uint4*)(ldst + ((shalf * 64 + 0) ^ swzs)) = r0;
        *(uint4*)(ldst + ((shalf * 64 + 16) ^ swzs)) = r1;
        *(uint4*)(ldst + ((shalf * 64 + 32) ^ swzs)) = r2;
        *(uint4*)(ldst + ((shalf * 64 + 48) ^ swzs)) = r3;
        // ---- prefetch next tile into the same regs ----
        if (t < 15) {
            const bf16* p = sbase + (size_t)(t + 1) * sstep;
            r0 = *(const uint4*)(p);
            r1 = *(const uint4*)(p + 8);
            r2 = *(const uint4*)(p + 16);
            r3 = *(const uint4*)(p + 24);
        }
        __syncthreads();

        // ---- S^T for BOTH qs halves; K fragments read once ----
        f32x4 s[2][4];
        __builtin_amdgcn_s_setprio(1);
        {
            bf16x8 ak[4];
#pragma unroll
            for (int js = 0; js < 4; ++js)
                ak[js] = *(const bf16x8*)(Kl + (js * 16 + lrow) * 128 + ((g * 16) ^ swzr));
#pragma unroll
            for (int qs = 0; qs < 2; ++qs)
#pragma unroll
                for (int js = 0; js < 4; ++js)
                    s[qs][js] = MFMA16(ak[js], bq[qs][0], zero4);
        }
        {
            bf16x8 ak[4];
#pragma unroll
            for (int js = 0; js < 4; ++js)
                ak[js] = *(const bf16x8*)(Kl + (js * 16 + lrow) * 128 + ((64 + g * 16) ^ swzr));
#pragma unroll
            for (int qs = 0; qs < 2; ++qs)
#pragma unroll
                for (int js = 0; js < 4; ++js)
                    s[qs][js] = MFMA16(ak[js], bq[qs][1], s[qs][js]);
        }
        __builtin_amdgcn_s_setprio(0);

        // ---- P = exp2(s) -> per-wave LDS (both qs) ----
#pragma unroll
        for (int qs = 0; qs < 2; ++qs) {
            const int qrow = qs * 16 + lrow;
#pragma unroll
            for (int js = 0; js < 4; ++js) {
                bf16x4 pk;
#pragma unroll
                for (int r = 0; r < 4; ++r) pk[r] = (bf16)fexp2(s[qs][js][r]);
                *(bf16x4*)(myp + ((qrow * 128 + js * 32 + g * 8) ^ swzr)) = pk;
            }
        }

        // ---- O += P V ; l += P @ ones.  V fragments read once ----
        __builtin_amdgcn_s_setprio(1);
#pragma unroll
        for (int ks2 = 0; ks2 < 2; ++ks2) {
            bf16x8 bv[4];
#pragma unroll
            for (int ds = 0; ds < 4; ++ds)
                bv[ds] = *(const bf16x8*)(Vl + (ds * 16 + lrow) * 128 +
                                          ((ks2 * 64 + g * 16) ^ swzr));
            bf16x8 ap0 = *(const bf16x8*)(myp + ((lrow * 128 + ks2 * 64 + g * 16) ^ swzr));
            bf16x8 ap1 = *(const bf16x8*)(myp + (((16 + lrow) * 128 + ks2 * 64 + g * 16) ^ swzr));
#pragma unroll
            for (int ds = 0; ds < 4; ++ds)
                accO[0][ds] = MFMA16(ap0, bv[ds], accO[0][ds]);
            l_acc[0] = MFMA16(ap0, ones, l_acc[0]);
#pragma unroll
            for (int ds = 0; ds < 4; ++ds)
                accO[1][ds] = MFMA16(ap1, bv[ds], accO[1][ds]);
            l_acc[1] = MFMA16(ap1, ones, l_acc[1]);
        }
        __builtin_amdgcn_s_setprio(0);
        __syncthreads();   // all waves done with this KV tile before overwrite
    }

    // ---- store partials (unnormalized) ----
#pragma unroll
    for (int qs = 0; qs < 2; ++qs)
#pragma unroll
        for (int ds = 0; ds < 4; ++ds)
#pragma unroll
            for (int r = 0; r < 4; ++r) {
                const int n = qbase + qs * 16 + 4 * g + r;
                Opart[((size_t)split * 4096 + n) * 512 + h * 64 + ds * 16 + lrow] =
                    (bf16)accO[qs][ds][r];
            }
    if (lrow == 0) {
#pragma unroll
        for (int qs = 0; qs < 2; ++qs)
#pragma unroll
            for (int r = 0; r < 4; ++r)
                lpart[((size_t)split * 8 + h) * 4096 + qbase + qs * 16 + 4 * g + r] =
                    l_acc[qs][r];
    }
}

// ---------------------------------------------------------------------------
// K5: fused combine + out-projection.
// y[c][n] = bo[c] + sum_j wo[c][j] * bf16( (sum_s Opart[s][n][j]) * linv[h][n] )
// with h = j>>6 and linv[h][n] = 1/sum_s lpart[s][h][n].  The K-loop is fully
// unrolled so h = k0>>6 is compile-time (linv[] stays in registers, rule #20).
// grid = dim3(64, 4): bx -> 64-n tile, by -> 64-c tile.  Eliminates the
// separate k_combine launch and the o_buf global round-trip.
// ---------------------------------------------------------------------------
__launch_bounds__(256)
__global__ void k_oproj(const bf16* __restrict__ wo_bf, const bf16* __restrict__ Opart,
                        const float* __restrict__ lpart, const float* __restrict__ bo,
                        float* __restrict__ ybuf) {
    const int lane = threadIdx.x & 63;
    const int w = threadIdx.x >> 6;
    const int i0 = blockIdx.y * 64 + w * 16;   // c
    const int j0 = blockIdx.x * 64;            // n
    const int lrow = lane & 15;
    const int lk = (lane >> 4) * 8;

    // per-lane linv[js][h]; all indices compile-time at use sites
    float linv[4][8];
#pragma unroll
    for (int js = 0; js < 4; ++js) {
        const int n = j0 + js * 16 + lrow;
#pragma unroll
        for (int h = 0; h < 8; ++h) {
            float l = lpart[(0 * 8 + h) * 4096 + n] + lpart[(1 * 8 + h) * 4096 + n] +
                      lpart[(2 * 8 + h) * 4096 + n] + lpart[(3 * 8 + h) * 4096 + n];
            linv[js][h] = 1.f / l;
        }
    }

    f32x4 acc[4];
#pragma unroll
    for (int b = 0; b < 4; ++b) acc[b] = (f32x4){0.f, 0.f, 0.f, 0.f};

    const size_t SP = (size_t)4096 * 512;   // split stride in Opart

#pragma unroll
    for (int k0 = 0; k0 < 512; k0 += 32) {
        const int h = k0 >> 6;   // compile-time per unrolled step (lk<32 never crosses)
        bf16x8 af = *(const bf16x8*)(wo_bf + (size_t)(i0 + lrow) * 512 + k0 + lk);
#pragma unroll
        for (int js = 0; js < 4; ++js) {
            const size_t nbase = (size_t)(j0 + js * 16 + lrow) * 512 + k0 + lk;
            bf16x8 b0 = *(const bf16x8*)(Opart + nbase);
            bf16x8 b1 = *(const bf16x8*)(Opart + SP + nbase);
            bf16x8 b2 = *(const bf16x8*)(Opart + 2 * SP + nbase);
            bf16x8 b3 = *(const bf16x8*)(Opart + 3 * SP + nbase);
            const float li = linv[js][h];
            bf16x8 bb;
#pragma unroll
            for (int e = 0; e < 8; ++e)
                bb[e] = (bf16)(((float)b0[e] + (float)b1[e] + (float)b2[e] + (float)b3[e]) * li);
            acc[js] = MFMA16(af, bb, acc[js]);
        }
    }

    const int rbase = (lane >> 4) * 4;
#pragma unroll
    for (int js = 0; js < 4; ++js)
#pragma unroll
        for (int r = 0; r < 4; ++r) {
            const int i = i0 + rbase + r;
            const int j = j0 + js * 16 + lrow;
            ybuf[(size_t)i * 4096 + j] = acc[js][r] + bo[i];
        }
}

// ---------------------------------------------------------------------------
// K6: fused depthwise 3x3 conv + 1x1 gate conv + sigmoid + multiply.
// Block owns 16 spatial positions (one quarter-row).  Phase 1: dw for all
// 256 channels into LDS (bf16 dwt_s for the GEMM, f32 acc_s for the mul).
// Phase 2: gate GEMM (M=256 c, N=16 n, K=256) from LDS + epilogue.
// Eliminates the dwout/dwt global round-trip and one launch boundary.
// 264 pitch -> 2-way (free) LDS conflict on B reads.
// ---------------------------------------------------------------------------
__launch_bounds__(256)
__global__ void k_dwgate(const float* __restrict__ y, const float* __restrict__ wdw,
                         const float* __restrict__ bdw, const bf16* __restrict__ wg_bf,
                         const float* __restrict__ bg, float* __restrict__ out) {
    __shared__ bf16 dwt_s[16][264];
    __shared__ float acc_s[16][264];
    const int tid = threadIdx.x;
    const int n0 = blockIdx.x * 16;
    const int yy = n0 >> 6;
    const int xx0 = n0 & 63;

    // ---- phase 1: depthwise 3x3 for 256 c x 16 xx (4 outputs/thread/iter) ----
    const int xxq = (tid & 3) * 4;
    const int gx = xx0 + xxq;
#pragma unroll
    for (int iter = 0; iter < 4; ++iter) {
        const int c = (tid >> 2) + iter * 64;
        const float* yc = y + (size_t)c * 4096;
        float w0r[3], w1r[3], w2r[3];
#pragma unroll
        for (int ky = 0; ky < 3; ++ky) {
            w0r[ky] = wdw[c * 9 + ky * 3 + 0];
            w1r[ky] = wdw[c * 9 + ky * 3 + 1];
            w2r[ky] = wdw[c * 9 + ky * 3 + 2];
        }
        const float b = bdw[c];
        float a0 = b, a1 = b, a2 = b, a3 = b;
#pragma unroll
        for (int ky = 0; ky < 3; ++ky) {
            const int ry = yy + ky - 1;
            if ((unsigned)ry < 64u) {
                const float* row = yc + ry * 64 + gx;
                const float4 v = *(const float4*)row;
                const float left = (gx > 0) ? row[-1] : 0.f;
                const float right = (gx < 60) ? row[4] : 0.f;
                a0 += w0r[ky] * left + w1r[ky] * v.x + w2r[ky] * v.y;
                a1 += w0r[ky] * v.x + w1r[ky] * v.y + w2r[ky] * v.z;
                a2 += w0r[ky] * v.y + w1r[ky] * v.z + w2r[ky] * v.w;
                a3 += w0r[ky] * v.z + w1r[ky] * v.w + w2r[ky] * right;
            }
        }
        dwt_s[xxq + 0][c] = (bf16)a0; acc_s[xxq + 0][c] = a0;
        dwt_s[xxq + 1][c] = (bf16)a1; acc_s[xxq + 1][c] = a1;
        dwt_s[xxq + 2][c] = (bf16)a2; acc_s[xxq + 2][c] = a2;
        dwt_s[xxq + 3][c] = (bf16)a3; acc_s[xxq + 3][c] = a3;
    }
    __syncthreads();

    // ---- phase 2: gate GEMM out[c][n] = acc_s[nl][c] * sigmoid(Sum + bg[c]) ----
    const int lane = tid & 63;
    const int w = tid >> 6;
    const int c0 = w * 64;
    const int lrow = lane & 15;
    const int lk = (lane >> 4) * 8;

    f32x4 gacc[4];
#pragma unroll
    for (int ai = 0; ai < 4; ++ai) gacc[ai] = (f32x4){0.f, 0.f, 0.f, 0.f};
#pragma unroll
    for (int k0 = 0; k0 < 256; k0 += 32) {
        const bf16x8 bfr = *(const bf16x8*)&dwt_s[lrow][k0 + lk];
#pragma unroll
        for (int ai = 0; ai < 4; ++ai) {
            const bf16x8 af = *(const bf16x8*)(wg_bf + (size_t)(c0 + ai * 16 + lrow) * 256 +
                                               k0 + lk);
            gacc[ai] = MFMA16(af, bfr, gacc[ai]);
        }
    }
    const int rbase = (lane >> 4) * 4;
#pragma unroll
    for (int ai = 0; ai < 4; ++ai)
#pragma unroll
        for (int r = 0; r < 4; ++r) {
            const int c = c0 + ai * 16 + rbase + r;
            const float g = gacc[ai][r] + bg[c];
            const float sg = 1.f / (1.f + __expf(-g));
            out[(size_t)c * 4096 + n0 + lrow] = acc_s[lrow][c] * sg;
        }
}

// ---------------------------------------------------------------------------
extern "C" void kernel_launch(void* const* d_in, const int* in_sizes, int n_in,
                              void* d_out, int out_size, void* d_ws, size_t ws_size,
                              hipStream_t stream) {
    const float* x   = (const float*)d_in[0];
    const float* wq1 = (const float*)d_in[1];
    const float* wk1 = (const float*)d_in[2];
    const float* wv1 = (const float*)d_in[3];
    const float* wq2 = (const float*)d_in[4];
    const float* wk2 = (const float*)d_in[5];
    const float* wv2 = (const float*)d_in[6];
    const float* wo  = (const float*)d_in[7];
    const float* bo  = (const float*)d_in[8];
    const float* wdw = (const float*)d_in[9];
    const float* bdw = (const float*)d_in[10];
    const float* wg  = (const float*)d_in[11];
    const float* bg  = (const float*)d_in[12];

    char* ws = (char*)d_ws;
    size_t off = 0;
    auto alloc = [&](size_t bytes) {
        char* p = ws + off;
        off += (bytes + 255) & ~(size_t)255;
        return p;
    };
    // persistent
    bf16*  q_buf = (bf16*)alloc((size_t)8 * 4096 * 64 * 2);
    bf16*  k_buf = (bf16*)alloc((size_t)8 * 4096 * 64 * 2);
    bf16*  vT    = (bf16*)alloc((size_t)8 * 64 * 4096 * 2);
    bf16*  wo_bf = (bf16*)alloc((size_t)256 * 512 * 2);
    bf16*  wg_bf = (bf16*)alloc((size_t)256 * 256 * 2);
    // union region (lifetimes disjoint):
    char* U = ws + off;
    //   phase 1 (pre-attn): xbf, Wq, Wk, Wv
    bf16*  xbf = (bf16*)U;
    bf16*  Wq  = (bf16*)(U + (size_t)2 * 1024 * 1024);
    bf16*  Wk  = (bf16*)(U + (size_t)2 * 1024 * 1024 + 262144);
    bf16*  Wv  = (bf16*)(U + (size_t)2 * 1024 * 1024 + 524288);
    //   phase 2 (attn -> oproj): Opart 16MB, lpart 512KB, ybuf 4MB (disjoint)
    bf16*  Opart = (bf16*)U;
    float* lpart = (float*)(U + (size_t)16 * 1024 * 1024);
    float* ybuf  = (float*)(U + (size_t)17 * 1024 * 1024);
    (void)ws_size; (void)in_sizes; (void)n_in; (void)out_size;

    const float QSCALE = 0.125f * 1.4426950408889634f;  // fold 1/sqrt(dk) * log2(e)

    k_pre<<<2560, 256, 0, stream>>>(x, xbf, wq1, wk1, wv1, wq2, wk2, wv2, wo, wg,
                                    Wq, Wk, Wv, wo_bf, wg_bf);
    k_qkv<<<768, 256, 0, stream>>>(xbf, Wq, Wk, Wv, q_buf, k_buf, vT, QSCALE);
    k_attn<<<1024, 256, 0, stream>>>(q_buf, k_buf, vT, Opart, lpart);
    k_oproj<<<dim3(64, 4), 256, 0, stream>>>(wo_bf, Opart, lpart, bo, ybuf);
    k_dwgate<<<256, 256, 0, stream>>>(ybuf, wdw, bdw, wg_bf, bg, (float*)d_out);
}

// Round 19
// 111.680 us; speedup vs baseline: 1.2589x; 1.2589x over previous
//
#include <hip/hip_runtime.h>

typedef __bf16 bf16;
typedef __bf16 bf16x4 __attribute__((ext_vector_type(4)));
typedef __bf16 bf16x8 __attribute__((ext_vector_type(8)));
typedef float f32x4 __attribute__((ext_vector_type(4)));

#define MFMA16(a, b, c) __builtin_amdgcn_mfma_f32_16x16x32_bf16((a), (b), (c), 0, 0, 0)

__device__ inline float fexp2(float x) {
    float r;
    asm("v_exp_f32 %0, %1" : "=v"(r) : "v"(x));
    return r;
}

// ---------------------------------------------------------------------------
// K1: fused pre-pass.  blocks 0-255: transpose x [256][4096] f32 ->
// xt [4096][256] bf16 (LDS-tiled).  blocks 256+: fused weights
// Wq/Wk/Wv = w2 @ w1 [512][256] bf16 + wo/wg -> bf16.
// ---------------------------------------------------------------------------
__global__ void k_pre(const float* __restrict__ x, bf16* __restrict__ xt,
                      const float* __restrict__ wq1, const float* __restrict__ wk1,
                      const float* __restrict__ wv1, const float* __restrict__ wq2,
                      const float* __restrict__ wk2, const float* __restrict__ wv2,
                      const float* __restrict__ wo, const float* __restrict__ wg,
                      bf16* __restrict__ Wq, bf16* __restrict__ Wk, bf16* __restrict__ Wv,
                      bf16* __restrict__ wo_bf, bf16* __restrict__ wg_bf) {
    __shared__ float tile[64][68];
    const int bx = blockIdx.x;
    if (bx < 256) {
        const int t = threadIdx.x;
        const int c0 = (bx & 3) * 64;
        const int n0 = (bx >> 2) * 64;
        {
            const int cr = t >> 4, nc = (t & 15) * 4;
#pragma unroll
            for (int i = 0; i < 4; ++i) {
                const float4 v = *(const float4*)(x + (size_t)(c0 + cr + i * 16) * 4096 + n0 + nc);
                tile[cr + i * 16][nc + 0] = v.x;
                tile[cr + i * 16][nc + 1] = v.y;
                tile[cr + i * 16][nc + 2] = v.z;
                tile[cr + i * 16][nc + 3] = v.w;
            }
        }
        __syncthreads();
        const int n = t >> 2, cc = (t & 3) * 16;
        bf16x8 o0, o1;
#pragma unroll
        for (int j = 0; j < 8; ++j) o0[j] = (bf16)tile[cc + j][n];
#pragma unroll
        for (int j = 0; j < 8; ++j) o1[j] = (bf16)tile[cc + 8 + j][n];
        bf16* dst = xt + (size_t)(n0 + n) * 256 + c0 + cc;
        *(bf16x8*)dst = o0;
        *(bf16x8*)(dst + 8) = o1;
    } else {
        int t = (bx - 256) * 256 + threadIdx.x;
        if (t < 393216) {                       // 3 * 512 * 256
            int which = t >> 17;
            int rem = t & 131071;
            int o = rem >> 8, c = rem & 255;
            const float* w1 = which == 0 ? wq1 : which == 1 ? wk1 : wv1;
            const float* w2 = which == 0 ? wq2 : which == 1 ? wk2 : wv2;
            float acc = 0.f;
#pragma unroll
            for (int j = 0; j < 32; ++j) acc += w2[o * 32 + j] * w1[j * 256 + c];
            bf16* W = which == 0 ? Wq : which == 1 ? Wk : Wv;
            W[o * 256 + c] = (bf16)acc;
        } else if (t < 524288) {                // wo: 256*512
            int idx = t - 393216;
            wo_bf[idx] = (bf16)wo[idx];
        } else if (t < 589824) {                // wg: 256*256
            int idx = t - 524288;
            wg_bf[idx] = (bf16)wg[idx];
        }
    }
}

// ---------------------------------------------------------------------------
// GEMM-NT body (tile 128x64): C[i][j] = sum_k A[i][k]*B[j][k].
// MODE 0: -> bf16 [j>>6][i][j&63] with scale; MODE 1: -> bf16 [i][j].
// ---------------------------------------------------------------------------
template <int MODE>
__device__ __forceinline__ void gemm_body(const bf16* __restrict__ A, const bf16* __restrict__ B,
                                          int K, float scale, void* __restrict__ outp,
                                          int bx, int by) {
    const int lane = threadIdx.x & 63;
    const int w = threadIdx.x >> 6;
    const int i0 = by * 128 + w * 32;
    const int j0 = bx * 64;
    const int lrow = lane & 15;
    const int lk = (lane >> 4) * 8;

    f32x4 acc[2][4];
#pragma unroll
    for (int a = 0; a < 2; ++a)
#pragma unroll
        for (int b = 0; b < 4; ++b) acc[a][b] = (f32x4){0.f, 0.f, 0.f, 0.f};

    for (int k0 = 0; k0 < K; k0 += 32) {
        bf16x8 af[2], bfr[4];
#pragma unroll
        for (int qs = 0; qs < 2; ++qs)
            af[qs] = *(const bf16x8*)(A + (size_t)(i0 + qs * 16 + lrow) * K + k0 + lk);
#pragma unroll
        for (int js = 0; js < 4; ++js)
            bfr[js] = *(const bf16x8*)(B + (size_t)(j0 + js * 16 + lrow) * K + k0 + lk);
#pragma unroll
        for (int qs = 0; qs < 2; ++qs)
#pragma unroll
            for (int js = 0; js < 4; ++js)
                acc[qs][js] = MFMA16(af[qs], bfr[js], acc[qs][js]);
    }

    const int rbase = (lane >> 4) * 4;
#pragma unroll
    for (int qs = 0; qs < 2; ++qs)
#pragma unroll
        for (int js = 0; js < 4; ++js)
#pragma unroll
            for (int r = 0; r < 4; ++r) {
                int i = i0 + qs * 16 + rbase + r;
                int j = j0 + js * 16 + lrow;
                float v = acc[qs][js][r];
                if (MODE == 0) {
                    ((bf16*)outp)[(size_t)(j >> 6) * (4096 * 64) + (size_t)i * 64 + (j & 63)] =
                        (bf16)(v * scale);
                } else {
                    ((bf16*)outp)[(size_t)i * 4096 + j] = (bf16)v;
                }
            }
}

// ---------------------------------------------------------------------------
// GEMM-NT (tile 64x64, 256-block fill for small outputs):
// MODE 2: -> f32 [i][j] + bias[i]; MODE 3: -> f32 mul*sigmoid(acc+bias).
// ---------------------------------------------------------------------------
template <int MODE>
__launch_bounds__(256)
__global__ void k_gemm64(const bf16* __restrict__ A, const bf16* __restrict__ B,
                         int K, void* __restrict__ outp,
                         const float* __restrict__ bias, const float* __restrict__ mul) {
    const int lane = threadIdx.x & 63;
    const int w = threadIdx.x >> 6;
    const int i0 = blockIdx.y * 64 + w * 16;
    const int j0 = blockIdx.x * 64;
    const int lrow = lane & 15;
    const int lk = (lane >> 4) * 8;

    f32x4 acc[4];
#pragma unroll
    for (int b = 0; b < 4; ++b) acc[b] = (f32x4){0.f, 0.f, 0.f, 0.f};

    for (int k0 = 0; k0 < K; k0 += 32) {
        bf16x8 af = *(const bf16x8*)(A + (size_t)(i0 + lrow) * K + k0 + lk);
        bf16x8 bfr[4];
#pragma unroll
        for (int js = 0; js < 4; ++js)
            bfr[js] = *(const bf16x8*)(B + (size_t)(j0 + js * 16 + lrow) * K + k0 + lk);
#pragma unroll
        for (int js = 0; js < 4; ++js)
            acc[js] = MFMA16(af, bfr[js], acc[js]);
    }

    const int rbase = (lane >> 4) * 4;
#pragma unroll
    for (int js = 0; js < 4; ++js)
#pragma unroll
        for (int r = 0; r < 4; ++r) {
            int i = i0 + rbase + r;
            int j = j0 + js * 16 + lrow;
            float v = acc[js][r];
            if (MODE == 2) {
                ((float*)outp)[(size_t)i * 4096 + j] = v + bias[i];
            } else {
                float g2 = v + bias[i];
                float sg = 1.f / (1.f + __expf(-g2));
                ((float*)outp)[(size_t)i * 4096 + j] = mul[(size_t)i * 4096 + j] * sg;
            }
        }
}

// ---------------------------------------------------------------------------
// K3: merged Q/K/V projection -- one 768-block launch.
// ---------------------------------------------------------------------------
__launch_bounds__(256)
__global__ void k_qkv(const bf16* __restrict__ xbf, const bf16* __restrict__ Wq,
                      const bf16* __restrict__ Wk, const bf16* __restrict__ Wv,
                      bf16* __restrict__ q_buf, bf16* __restrict__ k_buf,
                      bf16* __restrict__ vT, float qscale) {
    const int b = blockIdx.x;
    if (b < 256) {
        gemm_body<0>(xbf, Wq, 256, qscale, q_buf, b & 7, b >> 3);
    } else if (b < 512) {
        const int bb = b - 256;
        gemm_body<0>(xbf, Wk, 256, 1.0f, k_buf, bb & 7, bb >> 3);
    } else {
        const int bb = b - 512;
        gemm_body<1>(Wv, xbf, 256, 1.0f, vT, bb & 63, bb >> 6);
    }
}

// ---------------------------------------------------------------------------
// K4: flash attention, KV-split S=4, static-max softmax (exp2, shift=0).
// Best-measured config (R16, 54.2us): single 16KB KV buffer, zero4 C-operand,
// K/V fragments read once shared across qs halves, ones-MFMA row-sum,
// lambda-free, reg-staged prefetch, setprio on MFMA clusters.
// grid = 1024 (split<<8 | h<<5 | qt), block = 256 (4 waves x 32 q-rows).
// ---------------------------------------------------------------------------
__launch_bounds__(256)
__global__ void k_attn(const bf16* __restrict__ q, const bf16* __restrict__ k,
                       const bf16* __restrict__ vT, bf16* __restrict__ Opart,
                       float* __restrict__ lpart) {
    __shared__ char kvlds[16384];           // K [64 rows][128B] at 0, V at 8192
    __shared__ char plds[4][4096];          // per-wave P [32 rows][128B]
    const int tid = threadIdx.x;
    const int lane = tid & 63;
    const int w = tid >> 6;
    const int split = blockIdx.x >> 8;
    const int h = (blockIdx.x >> 5) & 7;
    const int qt = blockIdx.x & 31;
    const int qbase = qt * 128 + w * 32;
    const int lrow = lane & 15;
    const int g = lane >> 4;
    const int swzr = (lrow & 7) << 4;

    const bf16* qh = q + (size_t)h * 4096 * 64;
    const bf16* kh = k + (size_t)h * 4096 * 64;
    const bf16* vh = vT + (size_t)h * 64 * 4096;
    char* myp = plds[w];
    const char* Kl = kvlds;
    const char* Vl = kvlds + 8192;

    // staging geometry: threads 0-127 stage K (8KB), 128-255 stage V (8KB)
    const int isV = tid >> 7;
    const int srow = (tid & 127) >> 1;
    const int shalf = tid & 1;
    const int swzs = (srow & 7) << 4;
    char* ldst = kvlds + isV * 8192 + srow * 128;
    const bf16* sbase = isV ? (vh + (size_t)srow * 4096 + split * 1024 + shalf * 32)
                            : (kh + ((size_t)split * 1024 + srow) * 64 + shalf * 32);
    const size_t sstep = isV ? 64 : 64 * 64;   // elements per tile step

    // Q as B-fragments (col = q-row = lane&15)
    bf16x8 bq[2][2];
#pragma unroll
    for (int qs = 0; qs < 2; ++qs)
#pragma unroll
        for (int ks = 0; ks < 2; ++ks)
            bq[qs][ks] = *(const bf16x8*)(qh + (size_t)(qbase + qs * 16 + lrow) * 64 +
                                          ks * 32 + g * 8);

    f32x4 accO[2][4];
    f32x4 l_acc[2];
#pragma unroll
    for (int qs = 0; qs < 2; ++qs) {
#pragma unroll
        for (int ds = 0; ds < 4; ++ds) accO[qs][ds] = (f32x4){0.f, 0.f, 0.f, 0.f};
        l_acc[qs] = (f32x4){0.f, 0.f, 0.f, 0.f};
    }
    const f32x4 zero4 = (f32x4){0.f, 0.f, 0.f, 0.f};   // loop-invariant C=0
    bf16x8 ones;
#pragma unroll
    for (int i = 0; i < 8; ++i) ones[i] = (bf16)1.0f;

    // prologue: stage tile 0 into regs
    uint4 r0, r1, r2, r3;
    {
        const bf16* p = sbase;
        r0 = *(const uint4*)(p);
        r1 = *(const uint4*)(p + 8);
        r2 = *(const uint4*)(p + 16);
        r3 = *(const uint4*)(p + 24);
    }

    for (int t = 0; t < 16; ++t) {
        // ---- write staged tile to LDS (XOR-swizzled rows) ----
        *(uint4*)(ldst + ((shalf * 64 + 0) ^ swzs)) = r0;
        *(uint4*)(ldst + ((shalf * 64 + 16) ^ swzs)) = r1;
        *(uint4*)(ldst + ((shalf * 64 + 32) ^ swzs)) = r2;
        *(uint4*)(ldst + ((shalf * 64 + 48) ^ swzs)) = r3;
        // ---- prefetch next tile into the same regs ----
        if (t < 15) {
            const bf16* p = sbase + (size_t)(t + 1) * sstep;
            r0 = *(const uint4*)(p);
            r1 = *(const uint4*)(p + 8);
            r2 = *(const uint4*)(p + 16);
            r3 = *(const uint4*)(p + 24);
        }
        __syncthreads();

        // ---- S^T for BOTH qs halves; K fragments read once ----
        f32x4 s[2][4];
        __builtin_amdgcn_s_setprio(1);
        {
            bf16x8 ak[4];
#pragma unroll
            for (int js = 0; js < 4; ++js)
                ak[js] = *(const bf16x8*)(Kl + (js * 16 + lrow) * 128 + ((g * 16) ^ swzr));
#pragma unroll
            for (int qs = 0; qs < 2; ++qs)
#pragma unroll
                for (int js = 0; js < 4; ++js)
                    s[qs][js] = MFMA16(ak[js], bq[qs][0], zero4);
        }
        {
            bf16x8 ak[4];
#pragma unroll
            for (int js = 0; js < 4; ++js)
                ak[js] = *(const bf16x8*)(Kl + (js * 16 + lrow) * 128 + ((64 + g * 16) ^ swzr));
#pragma unroll
            for (int qs = 0; qs < 2; ++qs)
#pragma unroll
                for (int js = 0; js < 4; ++js)
                    s[qs][js] = MFMA16(ak[js], bq[qs][1], s[qs][js]);
        }
        __builtin_amdgcn_s_setprio(0);

        // ---- P = exp2(s) -> per-wave LDS (both qs) ----
#pragma unroll
        for (int qs = 0; qs < 2; ++qs) {
            const int qrow = qs * 16 + lrow;
#pragma unroll
            for (int js = 0; js < 4; ++js) {
                bf16x4 pk;
#pragma unroll
                for (int r = 0; r < 4; ++r) pk[r] = (bf16)fexp2(s[qs][js][r]);
                *(bf16x4*)(myp + ((qrow * 128 + js * 32 + g * 8) ^ swzr)) = pk;
            }
        }

        // ---- O += P V ; l += P @ ones.  V fragments read once ----
        __builtin_amdgcn_s_setprio(1);
#pragma unroll
        for (int ks2 = 0; ks2 < 2; ++ks2) {
            bf16x8 bv[4];
#pragma unroll
            for (int ds = 0; ds < 4; ++ds)
                bv[ds] = *(const bf16x8*)(Vl + (ds * 16 + lrow) * 128 +
                                          ((ks2 * 64 + g * 16) ^ swzr));
            bf16x8 ap0 = *(const bf16x8*)(myp + ((lrow * 128 + ks2 * 64 + g * 16) ^ swzr));
            bf16x8 ap1 = *(const bf16x8*)(myp + (((16 + lrow) * 128 + ks2 * 64 + g * 16) ^ swzr));
#pragma unroll
            for (int ds = 0; ds < 4; ++ds)
                accO[0][ds] = MFMA16(ap0, bv[ds], accO[0][ds]);
            l_acc[0] = MFMA16(ap0, ones, l_acc[0]);
#pragma unroll
            for (int ds = 0; ds < 4; ++ds)
                accO[1][ds] = MFMA16(ap1, bv[ds], accO[1][ds]);
            l_acc[1] = MFMA16(ap1, ones, l_acc[1]);
        }
        __builtin_amdgcn_s_setprio(0);
        __syncthreads();   // all waves done with this KV tile before overwrite
    }

    // ---- store partials (unnormalized) ----
#pragma unroll
    for (int qs = 0; qs < 2; ++qs)
#pragma unroll
        for (int ds = 0; ds < 4; ++ds)
#pragma unroll
            for (int r = 0; r < 4; ++r) {
                const int n = qbase + qs * 16 + 4 * g + r;
                Opart[((size_t)split * 4096 + n) * 512 + h * 64 + ds * 16 + lrow] =
                    (bf16)accO[qs][ds][r];
            }
    if (lrow == 0) {
#pragma unroll
        for (int qs = 0; qs < 2; ++qs)
#pragma unroll
            for (int r = 0; r < 4; ++r)
                lpart[((size_t)split * 8 + h) * 4096 + qbase + qs * 16 + 4 * g + r] =
                    l_acc[qs][r];
    }
}

// ---------------------------------------------------------------------------
// K5: combine partials -> o_buf bf16 [4096][512]
// ---------------------------------------------------------------------------
__global__ void k_combine(const bf16* __restrict__ Opart, const float* __restrict__ lpart,
                          bf16* __restrict__ o) {
    const int tid = blockIdx.x * 256 + threadIdx.x;   // 262144
    const int n = tid >> 6;
    const int c8 = (tid & 63) * 8;
    const int h = c8 >> 6;
    float acc[8] = {0, 0, 0, 0, 0, 0, 0, 0};
    float l = 0.f;
#pragma unroll
    for (int s = 0; s < 4; ++s) {
        const bf16x8 v = *(const bf16x8*)(Opart + ((size_t)s * 4096 + n) * 512 + c8);
#pragma unroll
        for (int j = 0; j < 8; ++j) acc[j] += (float)v[j];
        l += lpart[((size_t)s * 8 + h) * 4096 + n];
    }
    const float inv = 1.f / l;
    bf16x8 ov;
#pragma unroll
    for (int j = 0; j < 8; ++j) ov[j] = (bf16)(acc[j] * inv);
    *(bf16x8*)(o + (size_t)n * 512 + c8) = ov;
}

// ---------------------------------------------------------------------------
// K6: depthwise 3x3 conv (SAME), vectorized: 4 outputs/thread via float4.
// ---------------------------------------------------------------------------
__global__ void k_dw(const float* __restrict__ y, const float* __restrict__ wdw,
                     const float* __restrict__ bdw, float* __restrict__ dwout,
                     bf16* __restrict__ dwt) {
    int t = blockIdx.x * 256 + threadIdx.x;   // 262144
    int c = t >> 10, rem = t & 1023;
    int yy = rem >> 4, xx0 = (rem & 15) * 4;
    const float* yc = y + (size_t)c * 4096;
    float w0r[3], w1r[3], w2r[3];
#pragma unroll
    for (int ky = 0; ky < 3; ++ky) {
        w0r[ky] = wdw[c * 9 + ky * 3 + 0];
        w1r[ky] = wdw[c * 9 + ky * 3 + 1];
        w2r[ky] = wdw[c * 9 + ky * 3 + 2];
    }
    float b = bdw[c];
    float acc0 = b, acc1 = b, acc2 = b, acc3 = b;
#pragma unroll
    for (int ky = 0; ky < 3; ++ky) {
        int ry = yy + ky - 1;
        if ((unsigned)ry < 64u) {
            const float* row = yc + ry * 64 + xx0;
            float4 v = *(const float4*)row;
            float left = (xx0 > 0) ? row[-1] : 0.f;
            float right = (xx0 < 60) ? row[4] : 0.f;
            acc0 += w0r[ky] * left + w1r[ky] * v.x + w2r[ky] * v.y;
            acc1 += w0r[ky] * v.x + w1r[ky] * v.y + w2r[ky] * v.z;
            acc2 += w0r[ky] * v.y + w1r[ky] * v.z + w2r[ky] * v.w;
            acc3 += w0r[ky] * v.z + w1r[ky] * v.w + w2r[ky] * right;
        }
    }
    const int n = yy * 64 + xx0;
    *(float4*)(dwout + (size_t)c * 4096 + n) = make_float4(acc0, acc1, acc2, acc3);
    dwt[(size_t)(n + 0) * 256 + c] = (bf16)acc0;
    dwt[(size_t)(n + 1) * 256 + c] = (bf16)acc1;
    dwt[(size_t)(n + 2) * 256 + c] = (bf16)acc2;
    dwt[(size_t)(n + 3) * 256 + c] = (bf16)acc3;
}

// ---------------------------------------------------------------------------
extern "C" void kernel_launch(void* const* d_in, const int* in_sizes, int n_in,
                              void* d_out, int out_size, void* d_ws, size_t ws_size,
                              hipStream_t stream) {
    const float* x   = (const float*)d_in[0];
    const float* wq1 = (const float*)d_in[1];
    const float* wk1 = (const float*)d_in[2];
    const float* wv1 = (const float*)d_in[3];
    const float* wq2 = (const float*)d_in[4];
    const float* wk2 = (const float*)d_in[5];
    const float* wv2 = (const float*)d_in[6];
    const float* wo  = (const float*)d_in[7];
    const float* bo  = (const float*)d_in[8];
    const float* wdw = (const float*)d_in[9];
    const float* bdw = (const float*)d_in[10];
    const float* wg  = (const float*)d_in[11];
    const float* bg  = (const float*)d_in[12];

    char* ws = (char*)d_ws;
    size_t off = 0;
    auto alloc = [&](size_t bytes) {
        char* p = ws + off;
        off += (bytes + 255) & ~(size_t)255;
        return p;
    };
    // persistent
    bf16*  q_buf = (bf16*)alloc((size_t)8 * 4096 * 64 * 2);
    bf16*  k_buf = (bf16*)alloc((size_t)8 * 4096 * 64 * 2);
    bf16*  vT    = (bf16*)alloc((size_t)8 * 64 * 4096 * 2);
    bf16*  o_buf = (bf16*)alloc((size_t)4096 * 512 * 2);
    bf16*  wo_bf = (bf16*)alloc((size_t)256 * 512 * 2);
    bf16*  wg_bf = (bf16*)alloc((size_t)256 * 256 * 2);
    // union region (lifetimes disjoint):
    char* U = ws + off;
    bf16*  xbf = (bf16*)U;
    bf16*  Wq  = (bf16*)(U + (size_t)2 * 1024 * 1024);
    bf16*  Wk  = (bf16*)(U + (size_t)2 * 1024 * 1024 + 262144);
    bf16*  Wv  = (bf16*)(U + (size_t)2 * 1024 * 1024 + 524288);
    bf16*  Opart = (bf16*)U;                                   // 16MB
    float* lpart = (float*)(U + (size_t)16 * 1024 * 1024);     // 512KB
    float* ybuf  = (float*)U;
    float* dwout = (float*)(U + (size_t)4 * 1024 * 1024);
    bf16*  dwt   = (bf16*)(U + (size_t)8 * 1024 * 1024);
    (void)ws_size; (void)in_sizes; (void)n_in; (void)out_size;

    const float QSCALE = 0.125f * 1.4426950408889634f;  // fold 1/sqrt(dk) * log2(e)

    k_pre<<<2560, 256, 0, stream>>>(x, xbf, wq1, wk1, wv1, wq2, wk2, wv2, wo, wg,
                                    Wq, Wk, Wv, wo_bf, wg_bf);
    k_qkv<<<768, 256, 0, stream>>>(xbf, Wq, Wk, Wv, q_buf, k_buf, vT, QSCALE);
    k_attn<<<1024, 256, 0, stream>>>(q_buf, k_buf, vT, Opart, lpart);
    k_combine<<<1024, 256, 0, stream>>>(Opart, lpart, o_buf);
    k_gemm64<2><<<dim3(64, 4), 256, 0, stream>>>(wo_bf, o_buf, 512, ybuf, bo, nullptr);
    k_dw<<<1024, 256, 0, stream>>>(ybuf, wdw, bdw, dwout, dwt);
    k_gemm64<3><<<dim3(64, 4), 256, 0, stream>>>(wg_bf, dwt, 256, d_out, bg, dwout);
}